// Round 7
// baseline (276.308 us; speedup 1.0000x reference)
//
#include <hip/hip_runtime.h>
#include <hip/hip_bf16.h>

typedef __attribute__((ext_vector_type(8))) short short8;
typedef __attribute__((ext_vector_type(4))) float f32x4;
typedef __attribute__((ext_vector_type(16))) float f32x16;
typedef unsigned short u16;
typedef unsigned int u32;

// B=2, T=2048, C=2048, H=16, HD=128; M = B*T = 4096, K = N = 2048
__device__ __forceinline__ u16 f2bf(float f){
  __hip_bfloat16 h = __float2bfloat16(f);
  return *reinterpret_cast<u16*>(&h);
}

__device__ __forceinline__ void gld16(const void* g, void* l){
  __builtin_amdgcn_global_load_lds((const __attribute__((address_space(1))) void*)g,
                                   (__attribute__((address_space(3))) void*)l, 16, 0, 0);
}

#define SCHED0() __builtin_amdgcn_sched_barrier(0)

// ---------------- f32 -> bf16 convert ----------------
__global__ __launch_bounds__(256) void cvt_kernel(const float* __restrict__ src,
                                                  u16* __restrict__ dst, int n){
  int i0 = (blockIdx.x*256 + threadIdx.x)*4;
  int stride = gridDim.x*256*4;
  for (int i = i0; i < n; i += stride){
    float4 f = *reinterpret_cast<const float4*>(src + i);
    ushort4 u;
    u.x = f2bf(f.x); u.y = f2bf(f.y); u.z = f2bf(f.z); u.w = f2bf(f.w);
    *reinterpret_cast<ushort4*>(dst + i) = u;
  }
}

// ---------------- bf16 GEMM, 128x256 tile, BK=64, 8 waves (2Mx4N) ----------
// 2-phase schedule, 16 MFMA per barrier-pair (T3+T4):
//   p0: quads (0,0)+(1,0) — reads A-h0,A-h1,B-h0 (12 ds_read_b128);
//       stages Ah0,Bh0,Ah1(t+1) (4 gld16/thr)
//   p1: quads (1,1)+(0,1) — reads B-h1 (4 ds_read_b128);
//       stages Bh1(t+1) (2 gld16/thr)
// Counted waits (steady 6 in flight, never 0):
//   end p0: vmcnt(4) -> Bh1(t) [issued p1(t-1)] landed
//   end p1: vmcnt(2) -> Ah0,Bh0,Ah1(t+1) [issued p0(t)] landed
// LDS 96KB = 2 slots x (A 16KB + B 32KB), 128B rows, chunk swz c^(r&7)
// (inverse-swz global source, linear LDS dest).
__device__ __forceinline__ void gemm256_body(const u16* __restrict__ A,
    const u16* __restrict__ W, void* __restrict__ outp, float scale, int epi)
{
  __shared__ alignas(16) u16 Lds[49152];   // 96 KiB
  const int tid = threadIdx.x;
  const int w = tid>>6, l = tid&63;
  const int l15 = l&15, lg = l>>4;
  const int wm = w&1, wn = w>>1;           // 2M x 4N
  const int row0 = blockIdx.y*128, col0 = blockIdx.x*256;
  constexpr int K = 2048;
  constexpr int NT = K/64;

  f32x4 acc[4][4];
  #pragma unroll
  for (int i=0;i<4;i++)
    #pragma unroll
    for (int j=0;j<4;j++)
      #pragma unroll
      for (int r=0;r<4;r++) acc[i][j][r] = 0.f;

  const int sArow = tid>>3,        sAcol = (((tid&7) ^ ((tid>>3)&7)))*8;
  int sBrow[2], sBcol[2];
  #pragma unroll
  for (int p=0;p<2;p++){
    int s = p*512 + tid;
    sBrow[p] = s>>3;  sBcol[p] = ((s&7) ^ ((s>>3)&7))*8;
  }

  auto stageAh = [&](int slot, int kt, int h){
    gld16(A + (size_t)(row0 + h*64 + sArow)*K + kt*64 + sAcol,
          (char*)Lds + slot*49152 + h*8192 + w*1024);
  };
  auto stageBh = [&](int slot, int kt, int h){
    #pragma unroll
    for (int p=0;p<2;p++)
      gld16(W + (size_t)(col0 + h*128 + sBrow[p])*K + kt*64 + sBcol[p],
            (char*)Lds + slot*49152 + 16384 + h*16384 + p*8192 + w*1024);
  };
  auto readA = [&](int slot, int mh, short8 (&af)[2][2]){
    #pragma unroll
    for (int ks=0;ks<2;ks++)
      #pragma unroll
      for (int i=0;i<2;i++){
        int r = wm*32 + i*16 + l15;
        int byt = slot*49152 + mh*8192 + r*128 + (((ks*4+lg) ^ (r&7))<<4);
        af[ks][i] = *reinterpret_cast<const short8*>((const char*)Lds + byt);
      }
  };
  auto readB = [&](int slot, int nh, short8 (&bf)[2][2]){
    #pragma unroll
    for (int ks=0;ks<2;ks++)
      #pragma unroll
      for (int j=0;j<2;j++){
        int r = wn*32 + j*16 + l15;
        int byt = slot*49152 + 16384 + nh*16384 + r*128 + (((ks*4+lg) ^ (r&7))<<4);
        bf[ks][j] = *reinterpret_cast<const short8*>((const char*)Lds + byt);
      }
  };

  short8 a0[2][2], a1[2][2], bb[2][2];
  auto quad = [&](const short8 (&af)[2][2], int mh, int nh){
    #pragma unroll
    for (int ks=0;ks<2;ks++)
      #pragma unroll
      for (int i=0;i<2;i++)
        #pragma unroll
        for (int j=0;j<2;j++)
          acc[mh*2+i][nh*2+j] = __builtin_amdgcn_mfma_f32_16x16x32_bf16(
              af[ks][i], bb[ks][j], acc[mh*2+i][nh*2+j], 0, 0, 0);
  };

  // prologue: stage tile 0 fully into slot 0 (6 loads/thr), full drain once
  stageAh(0,0,0); stageBh(0,0,0); stageAh(0,0,1); stageBh(0,0,1);
  __syncthreads();

  int cur = 0;
  for (int t=0; t<NT; ++t){
    int nxt = (t+1) & (NT-1);   // wrap keeps vmcnt accounting uniform
    int ns = cur^1;
    // ---- p0: quads (0,0)+(1,0); stage Ah0,Bh0,Ah1(t+1) ----
    readA(cur, 0, a0);
    readA(cur, 1, a1);
    readB(cur, 0, bb);
    stageAh(ns, nxt, 0);
    stageBh(ns, nxt, 0);
    stageAh(ns, nxt, 1);
    SCHED0();
    __builtin_amdgcn_s_barrier();
    asm volatile("s_waitcnt lgkmcnt(0)" ::: "memory");
    SCHED0();
    __builtin_amdgcn_s_setprio(1);
    quad(a0, 0, 0);
    quad(a1, 1, 0);
    __builtin_amdgcn_s_setprio(0);
    SCHED0();
    asm volatile("s_waitcnt vmcnt(4)" ::: "memory");   // Bh1(t) landed
    __builtin_amdgcn_s_barrier();
    SCHED0();
    // ---- p1: quads (1,1)+(0,1); stage Bh1(t+1) ----
    readB(cur, 1, bb);
    stageBh(ns, nxt, 1);
    SCHED0();
    __builtin_amdgcn_s_barrier();
    asm volatile("s_waitcnt lgkmcnt(0)" ::: "memory");
    SCHED0();
    __builtin_amdgcn_s_setprio(1);
    quad(a1, 1, 1);
    quad(a0, 0, 1);
    __builtin_amdgcn_s_setprio(0);
    SCHED0();
    asm volatile("s_waitcnt vmcnt(2)" ::: "memory");   // Ah0,Bh0,Ah1(t+1) landed
    __builtin_amdgcn_s_barrier();
    SCHED0();
    cur ^= 1;
  }

  // epilogue: C/D layout col = lane&15, row = (lane>>4)*4 + r  [m89/m91]
  if (epi == 0){          // Q/K: bf16 scatter to [b][h][t][d]
    u16* O = (u16*)outp;
    #pragma unroll
    for (int mi=0;mi<4;mi++)
      #pragma unroll
      for (int nj=0;nj<4;nj++)
        #pragma unroll
        for (int r=0;r<4;r++){
          int m = row0 + (mi>>1)*64 + wm*32 + (mi&1)*16 + lg*4 + r;
          int n = col0 + (nj>>1)*128 + wn*32 + (nj&1)*16 + l15;
          int b = m >> 11, tt = m & 2047;
          int h = n >> 7,  d = n & 127;
          O[(((size_t)(b*16 + h)*2048 + tt)<<7) + d] = f2bf(acc[mi][nj][r] * scale);
        }
  } else if (epi == 2){   // V: bf16 V^T [b][h][d][t]
    u16* O = (u16*)outp;
    #pragma unroll
    for (int mi=0;mi<4;mi++)
      #pragma unroll
      for (int nj=0;nj<4;nj++){
        int m0 = row0 + (mi>>1)*64 + wm*32 + (mi&1)*16 + lg*4;
        int n  = col0 + (nj>>1)*128 + wn*32 + (nj&1)*16 + l15;
        int b = m0 >> 11, tt = m0 & 2047;
        int h = n >> 7,  d = n & 127;
        ushort4 u;
        u.x = f2bf(acc[mi][nj][0]); u.y = f2bf(acc[mi][nj][1]);
        u.z = f2bf(acc[mi][nj][2]); u.w = f2bf(acc[mi][nj][3]);
        *reinterpret_cast<ushort4*>(&O[(((size_t)(b*16 + h)<<7) + d)*2048 + tt]) = u;
      }
  } else {                // out-proj: f32 row-major [m][n]
    float* O = (float*)outp;
    #pragma unroll
    for (int mi=0;mi<4;mi++)
      #pragma unroll
      for (int nj=0;nj<4;nj++)
        #pragma unroll
        for (int r=0;r<4;r++){
          int m = row0 + (mi>>1)*64 + wm*32 + (mi&1)*16 + lg*4 + r;
          int n = col0 + (nj>>1)*128 + wn*32 + (nj&1)*16 + l15;
          O[(size_t)m*2048 + n] = acc[mi][nj][r];
        }
  }
}

__global__ __launch_bounds__(512,2) void gemm_qkv(const u16* __restrict__ A,
    const u16* __restrict__ Wq, const u16* __restrict__ Wk, const u16* __restrict__ Wv,
    u16* __restrict__ qo, u16* __restrict__ ko, u16* __restrict__ vt, float qscale)
{
  const u16* W; void* O; float sc; int epi;
  if (blockIdx.z == 0){ W = Wq; O = qo; sc = qscale; epi = 0; }
  else if (blockIdx.z == 1){ W = Wk; O = ko; sc = 1.f; epi = 0; }
  else { W = Wv; O = vt; sc = 1.f; epi = 2; }
  gemm256_body(A, W, O, sc, epi);
}

__global__ __launch_bounds__(512,2) void gemm_out(const u16* __restrict__ A,
    const u16* __restrict__ W, float* __restrict__ O)
{
  gemm256_body(A, W, O, 1.f, 1);
}

// ---------------- flash attention, 32x32x16 MFMA, swapped QK^T -------------
// (unchanged from round 5)
__global__ __launch_bounds__(256,2) void attn_kernel(
    const u16* __restrict__ Q, const u16* __restrict__ Kg,
    const u16* __restrict__ Vt, u16* __restrict__ Y)
{
  __shared__ alignas(16) u16 Ks[2][64*128];
  __shared__ alignas(16) u16 Vs[2][64*128];
  const int tid = threadIdx.x;
  const int w = tid>>6, l = tid&63;
  const int l31 = l&31, hi = l>>5;
  const int bh_swz = ((blockIdx.x&7)*64 + (blockIdx.x>>3));
  const int bh = bh_swz >> 4;
  const int q0 = (bh_swz & 15) * 128;

  short8 qf[8];
  #pragma unroll
  for (int ds=0; ds<8; ds++)
    qf[ds] = *reinterpret_cast<const short8*>(
        Q + ((size_t)bh*2048 + q0 + w*32 + l31)*128 + ds*16 + hi*8);

  f32x16 accO[4];
  #pragma unroll
  for (int dt=0;dt<4;dt++)
    #pragma unroll
    for (int r=0;r<16;r++) accO[dt][r] = 0.f;
  float mrun = -1e30f, lrun = 0.f;

  int krow_[4], kcol_[4], vd_[4], vkv_[4];
  #pragma unroll
  for (int p=0;p<4;p++){
    int s = p*256 + tid;
    int r = s>>4, c = s&15;
    int cu = c ^ (r&15);
    krow_[p] = r;  kcol_[p] = cu*8;
    vd_[p] = r*2 + (cu>>3);  vkv_[p] = (cu&7)*8;
  }

  auto stage = [&](int buf, int kvt){
    int kv0 = kvt*64;
    #pragma unroll
    for (int p=0;p<4;p++)
      gld16(Kg + ((size_t)bh*2048 + kv0 + krow_[p])*128 + kcol_[p],
            &Ks[buf][(size_t)(p*256 + w*64)*8]);
    #pragma unroll
    for (int p=0;p<4;p++)
      gld16(Vt + ((size_t)bh*128 + vd_[p])*2048 + kv0 + vkv_[p],
            &Vs[buf][(size_t)(p*256 + w*64)*8]);
  };

  stage(0, 0);
  __syncthreads();

  int cur = 0;
  for (int kvt=0; kvt<32; ++kvt){
    if (kvt+1 < 32) stage(cur^1, kvt+1);

    f32x16 accS[2];
    #pragma unroll
    for (int kt=0;kt<2;kt++)
      #pragma unroll
      for (int r=0;r<16;r++) accS[kt][r] = 0.f;
    #pragma unroll
    for (int kt=0;kt<2;kt++){
      #pragma unroll
      for (int ds=0;ds<8;ds++){
        int row = kt*32 + l31;
        int byt = row*256 + (((ds*2 + hi) ^ (row&15))<<4);
        short8 kf = *reinterpret_cast<const short8*>((const char*)(&Ks[cur][0]) + byt);
        accS[kt] = __builtin_amdgcn_mfma_f32_32x32x16_bf16(kf, qf[ds], accS[kt], 0, 0, 0);
      }
    }

    float pmax = accS[0][0];
    #pragma unroll
    for (int kt=0;kt<2;kt++)
      #pragma unroll
      for (int r=0;r<16;r++) pmax = fmaxf(pmax, accS[kt][r]);
    pmax = fmaxf(pmax, __shfl_xor(pmax, 32, 64));
    if (__any(pmax > mrun + 8.f)){
      float mn = fmaxf(mrun, pmax);
      float c = __expf(mrun - mn);
      mrun = mn;
      lrun *= c;
      #pragma unroll
      for (int r=0;r<16;r++){
        int qrow = (r&3) + 8*(r>>2) + 4*hi;
        float cr = __shfl(c, qrow, 64);
        #pragma unroll
        for (int dt=0;dt<4;dt++) accO[dt][r] *= cr;
      }
    }

    float rs = 0.f;
    short8 pa[4];
    #pragma unroll
    for (int kt=0;kt<2;kt++){
      #pragma unroll
      for (int b=0;b<2;b++){
        float e0 = __expf(accS[kt][b*8+0] - mrun);
        float e1 = __expf(accS[kt][b*8+1] - mrun);
        float e2 = __expf(accS[kt][b*8+2] - mrun);
        float e3 = __expf(accS[kt][b*8+3] - mrun);
        float e4 = __expf(accS[kt][b*8+4] - mrun);
        float e5 = __expf(accS[kt][b*8+5] - mrun);
        float e6 = __expf(accS[kt][b*8+6] - mrun);
        float e7 = __expf(accS[kt][b*8+7] - mrun);
        rs += (e0+e1)+(e2+e3)+(e4+e5)+(e6+e7);
        u32 x01 = (u32)f2bf(e0) | ((u32)f2bf(e1)<<16);
        u32 x23 = (u32)f2bf(e2) | ((u32)f2bf(e3)<<16);
        u32 y01 = (u32)f2bf(e4) | ((u32)f2bf(e5)<<16);
        u32 y23 = (u32)f2bf(e6) | ((u32)f2bf(e7)<<16);
        u32 sx_x01 = __shfl_xor(x01, 32, 64);
        u32 sx_x23 = __shfl_xor(x23, 32, 64);
        u32 sx_y01 = __shfl_xor(y01, 32, 64);
        u32 sx_y23 = __shfl_xor(y23, 32, 64);
        int4 wv;
        wv.x = (int)(hi ? sx_y01 : x01);
        wv.y = (int)(hi ? sx_y23 : x23);
        wv.z = (int)(hi ? y01 : sx_x01);
        wv.w = (int)(hi ? y23 : sx_x23);
        pa[kt*2+b] = *reinterpret_cast<short8*>(&wv);
      }
    }
    rs += __shfl_xor(rs, 32, 64);
    lrun += rs;

    #pragma unroll
    for (int dt=0;dt<4;dt++){
      #pragma unroll
      for (int ks=0;ks<4;ks++){
        int d = dt*32 + l31;
        int cu = (d&1)*8 + ks*2 + hi;
        int byt = (d>>1)*256 + ((cu ^ ((d>>1)&15))<<4);
        short8 vf = *reinterpret_cast<const short8*>((const char*)(&Vs[cur][0]) + byt);
        accO[dt] = __builtin_amdgcn_mfma_f32_32x32x16_bf16(pa[ks], vf, accO[dt], 0, 0, 0);
      }
    }

    __syncthreads();
    cur ^= 1;
  }

  const int b_ = bh >> 4, h_ = bh & 15;
  float inv = 1.f / lrun;
  #pragma unroll
  for (int r=0;r<16;r++){
    int qrow = (r&3) + 8*(r>>2) + 4*hi;
    float lr = __shfl(inv, qrow, 64);
    int t = q0 + w*32 + qrow;
    #pragma unroll
    for (int dt=0;dt<4;dt++){
      int d = dt*32 + l31;
      Y[((size_t)b_*2048 + t)*2048 + h_*128 + d] = f2bf(accO[dt][r] * lr);
    }
  }
}

// ---------------- launch ----------------
extern "C" void kernel_launch(void* const* d_in, const int* in_sizes, int n_in,
                              void* d_out, int out_size, void* d_ws, size_t ws_size,
                              hipStream_t stream)
{
  const float* x  = (const float*)d_in[0];
  const float* Wq = (const float*)d_in[1];
  const float* Wk = (const float*)d_in[2];
  const float* Wv = (const float*)d_in[3];
  const float* Wo = (const float*)d_in[4];
  float* out = (float*)d_out;
  char* ws = (char*)d_ws;

  const size_t MB = 1024*1024;
  u16* xb  = (u16*)(ws);            // 16 MiB bf16 x
  u16* wqb = (u16*)(ws + 16*MB);    //  8 MiB
  u16* wkb = (u16*)(ws + 24*MB);    //  8 MiB
  u16* wvb = (u16*)(ws + 32*MB);    //  8 MiB
  u16* wob = (u16*)(ws + 40*MB);    //  8 MiB
  u16* qb  = (u16*)(ws + 48*MB);    // 16 MiB [b][h][t][d]
  u16* kb  = (u16*)(ws + 64*MB);    // 16 MiB [b][h][t][d]
  u16* vtb = (u16*)(ws + 80*MB);    // 16 MiB [b][h][d][t]
  u16* yb  = wqb;                   // 16 MiB overlay: wq/wk dead after gemm_qkv

  cvt_kernel<<<2048, 256, 0, stream>>>(x,  xb,  4096*2048);
  cvt_kernel<<<1024, 256, 0, stream>>>(Wq, wqb, 2048*2048);
  cvt_kernel<<<1024, 256, 0, stream>>>(Wk, wkb, 2048*2048);
  cvt_kernel<<<1024, 256, 0, stream>>>(Wv, wvb, 2048*2048);
  cvt_kernel<<<1024, 256, 0, stream>>>(Wo, wob, 2048*2048);

  const float qscale = 0.08838834764831845f;  // 1/sqrt(128)
  gemm_qkv<<<dim3(8,32,3), 512, 0, stream>>>(xb, wqb, wkb, wvb, qb, kb, vtb, qscale);
  attn_kernel<<<512, 256, 0, stream>>>(qb, kb, vtb, yb);
  gemm_out<<<dim3(8,32), 512, 0, stream>>>(yb, wob, out);
}

// Round 8
// 263.601 us; speedup vs baseline: 1.0482x; 1.0482x over previous
//
#include <hip/hip_runtime.h>
#include <hip/hip_bf16.h>

typedef __attribute__((ext_vector_type(8))) short short8;
typedef __attribute__((ext_vector_type(4))) float f32x4;
typedef __attribute__((ext_vector_type(16))) float f32x16;
typedef unsigned short u16;
typedef unsigned int u32;

// B=2, T=2048, C=2048, H=16, HD=128; M = B*T = 4096, K = N = 2048
__device__ __forceinline__ u16 f2bf(float f){
  __hip_bfloat16 h = __float2bfloat16(f);
  return *reinterpret_cast<u16*>(&h);
}

__device__ __forceinline__ void gld16(const void* g, void* l){
  __builtin_amdgcn_global_load_lds((const __attribute__((address_space(1))) void*)g,
                                   (__attribute__((address_space(3))) void*)l, 16, 0, 0);
}

#define SCHED0() __builtin_amdgcn_sched_barrier(0)

// ---------------- f32 -> bf16 convert ----------------
__global__ __launch_bounds__(256) void cvt_kernel(const float* __restrict__ src,
                                                  u16* __restrict__ dst, int n){
  int i0 = (blockIdx.x*256 + threadIdx.x)*4;
  int stride = gridDim.x*256*4;
  for (int i = i0; i < n; i += stride){
    float4 f = *reinterpret_cast<const float4*>(src + i);
    ushort4 u;
    u.x = f2bf(f.x); u.y = f2bf(f.y); u.z = f2bf(f.z); u.w = f2bf(f.w);
    *reinterpret_cast<ushort4*>(dst + i) = u;
  }
}

// ---------------- bf16 GEMM, 128x256 tile, BK=64, 8 waves (2Mx2Nx2K) -------
// K-split waves: wave (wm,wn,wk) computes 64x128 output over k-half wk only;
// wk pairs reduce via LDS at epilogue. Per-wave/K-tile: 12 ds_read_b128 ->
// 32 MFMA (43.7 FLOP/LDS-byte vs 32.8 before).
// TRI-buffered LDS (A 3x16KB + B 3x32KB = 144KB), depth-2 prefetch:
//   tile t issues A(t+2)[2 gld/thr], B(t+2)[4 gld/thr]
//   end-of-tile: vmcnt(6) drains A(t+1),B(t+1) (issued 1 tile ago; 2-tile
//   latency cover), leaves A(t+2),B(t+2) in flight. ONE barrier per K-tile.
//   Slot (t+2)%3 never collides with live read slots t%3,(t+1)%3.
// Rows 128B, chunk swizzle c^(r&7) via inverse-swizzled global source.
__device__ __forceinline__ void gemm256_body(const u16* __restrict__ A,
    const u16* __restrict__ W, void* __restrict__ outp, float scale, int epi)
{
  __shared__ alignas(16) u16 Lds[73728];   // 144 KiB: A@0 (3x8192 u16), B@24576 (3x16384)
  const int tid = threadIdx.x;
  const int w = tid>>6, l = tid&63;
  const int l15 = l&15, lg = l>>4;
  const int wm = w&1, wn = (w>>1)&1, wk = w>>2;   // 2M x 2N x 2K
  const int row0 = blockIdx.y*128, col0 = blockIdx.x*256;
  constexpr int K = 2048;
  constexpr int NT = K/64;

  f32x4 acc[4][8];
  #pragma unroll
  for (int i=0;i<4;i++)
    #pragma unroll
    for (int j=0;j<8;j++)
      #pragma unroll
      for (int r=0;r<4;r++) acc[i][j][r] = 0.f;

  // staging maps (inverse-swizzled source, linear LDS dest), 128B rows
  int sBrow[4], sBcol[4];
  #pragma unroll
  for (int p=0;p<4;p++){
    int s = p*512 + tid;
    sBrow[p] = s>>3;  sBcol[p] = ((s&7) ^ ((s>>3)&7))*8;
  }
  const int sArow0 = sBrow[0], sAcol0 = sBcol[0];
  const int sArow1 = sBrow[1], sAcol1 = sBcol[1];

  auto stageA = [&](int slot, int kt){   // 128x64 = 16KB, 2 gld/thr
    gld16(A + (size_t)(row0 + sArow0)*K + kt*64 + sAcol0,
          &Lds[slot*8192 + (size_t)(w*64)*8]);
    gld16(A + (size_t)(row0 + sArow1)*K + kt*64 + sAcol1,
          &Lds[slot*8192 + (size_t)(512 + w*64)*8]);
  };
  auto stageB = [&](int slot, int kt){   // 256x64 = 32KB, 4 gld/thr
    #pragma unroll
    for (int p=0;p<4;p++)
      gld16(W + (size_t)(col0 + sBrow[p])*K + kt*64 + sBcol[p],
            &Lds[24576 + slot*16384 + (size_t)(p*512 + w*64)*8]);
  };
  auto readA = [&](int slot, short8 (&af)[4]){
    #pragma unroll
    for (int i=0;i<4;i++){
      int r = wm*64 + i*16 + l15;
      int byt = slot*16384 + r*128 + (((wk*4+lg) ^ (r&7))<<4);
      af[i] = *reinterpret_cast<const short8*>((const char*)Lds + byt);
    }
  };
  auto readB = [&](int slot, short8 (&bf)[8]){
    #pragma unroll
    for (int j=0;j<8;j++){
      int r = wn*128 + j*16 + l15;
      int byt = 49152 + slot*32768 + r*128 + (((wk*4+lg) ^ (r&7))<<4);
      bf[j] = *reinterpret_cast<const short8*>((const char*)Lds + byt);
    }
  };

  // prologue: issue tiles 0 and 1; drain tile 0, keep tile 1 in flight (6)
  stageA(0, 0); stageB(0, 0);
  stageA(1, 1); stageB(1, 1);
  SCHED0();
  asm volatile("s_waitcnt vmcnt(6)" ::: "memory");
  __builtin_amdgcn_s_barrier();
  SCHED0();

  int sl = 0;
  for (int t=0; t<NT; ++t){
    int st = sl+2; if (st>=3) st-=3;
    int tn = (t+2) & (NT-1);          // wrap: uniform accounting, never read
    stageA(st, tn);
    stageB(st, tn);
    short8 af[4], bf[8];
    readA(sl, af);
    readB(sl, bf);
    asm volatile("s_waitcnt lgkmcnt(0)" ::: "memory");
    SCHED0();
    __builtin_amdgcn_s_setprio(1);
    #pragma unroll
    for (int i=0;i<4;i++)
      #pragma unroll
      for (int j=0;j<8;j++)
        acc[i][j] = __builtin_amdgcn_mfma_f32_16x16x32_bf16(af[i], bf[j], acc[i][j], 0, 0, 0);
    __builtin_amdgcn_s_setprio(0);
    SCHED0();
    asm volatile("s_waitcnt vmcnt(6)" ::: "memory");   // A,B(t+1) landed
    __builtin_amdgcn_s_barrier();
    SCHED0();
    sl = sl+1; if (sl>=3) sl = 0;
  }

  // ---- cross-wave K-reduce: wk=1 -> LDS -> wk=0 adds ----
  __syncthreads();                     // full drain incl. in-flight stages
  float* R = (float*)Lds;              // 128KB as f32 (fits in 144KB)
  const int pair = wm*2 + wn;          // 0..3, 32KB each
  if (wk == 1){
    #pragma unroll
    for (int i=0;i<4;i++)
      #pragma unroll
      for (int j=0;j<8;j++)
        *reinterpret_cast<f32x4*>(&R[pair*8192 + (i*8+j)*256 + l*4]) = acc[i][j];
  }
  __syncthreads();
  if (wk == 0){
    #pragma unroll
    for (int i=0;i<4;i++)
      #pragma unroll
      for (int j=0;j<8;j++){
        f32x4 o = *reinterpret_cast<const f32x4*>(&R[pair*8192 + (i*8+j)*256 + l*4]);
        #pragma unroll
        for (int r=0;r<4;r++) acc[i][j][r] += o[r];
      }

    // epilogue (wk=0 waves only): C/D col = lane&15, row = (lane>>4)*4 + r
    if (epi == 0){          // Q/K: bf16 scatter to [b][h][t][d]
      u16* O = (u16*)outp;
      #pragma unroll
      for (int i=0;i<4;i++)
        #pragma unroll
        for (int j=0;j<8;j++)
          #pragma unroll
          for (int r=0;r<4;r++){
            int m = row0 + wm*64 + i*16 + lg*4 + r;
            int n = col0 + wn*128 + j*16 + l15;
            int b = m >> 11, tt = m & 2047;
            int h = n >> 7,  d = n & 127;
            O[(((size_t)(b*16 + h)*2048 + tt)<<7) + d] = f2bf(acc[i][j][r] * scale);
          }
    } else if (epi == 2){   // V: bf16 V^T [b][h][d][t]
      u16* O = (u16*)outp;
      #pragma unroll
      for (int i=0;i<4;i++)
        #pragma unroll
        for (int j=0;j<8;j++){
          int m0 = row0 + wm*64 + i*16 + lg*4;
          int n  = col0 + wn*128 + j*16 + l15;
          int b = m0 >> 11, tt = m0 & 2047;
          int h = n >> 7,  d = n & 127;
          ushort4 u;
          u.x = f2bf(acc[i][j][0]); u.y = f2bf(acc[i][j][1]);
          u.z = f2bf(acc[i][j][2]); u.w = f2bf(acc[i][j][3]);
          *reinterpret_cast<ushort4*>(&O[(((size_t)(b*16 + h)<<7) + d)*2048 + tt]) = u;
        }
    } else {                // out-proj: f32 row-major [m][n]
      float* O = (float*)outp;
      #pragma unroll
      for (int i=0;i<4;i++)
        #pragma unroll
        for (int j=0;j<8;j++)
          #pragma unroll
          for (int r=0;r<4;r++){
            int m = row0 + wm*64 + i*16 + lg*4 + r;
            int n = col0 + wn*128 + j*16 + l15;
            O[(size_t)m*2048 + n] = acc[i][j][r];
          }
    }
  }
}

__global__ __launch_bounds__(512,2) void gemm_qkv(const u16* __restrict__ A,
    const u16* __restrict__ Wq, const u16* __restrict__ Wk, const u16* __restrict__ Wv,
    u16* __restrict__ qo, u16* __restrict__ ko, u16* __restrict__ vt, float qscale)
{
  const u16* W; void* O; float sc; int epi;
  if (blockIdx.z == 0){ W = Wq; O = qo; sc = qscale; epi = 0; }
  else if (blockIdx.z == 1){ W = Wk; O = ko; sc = 1.f; epi = 0; }
  else { W = Wv; O = vt; sc = 1.f; epi = 2; }
  gemm256_body(A, W, O, sc, epi);
}

__global__ __launch_bounds__(512,2) void gemm_out(const u16* __restrict__ A,
    const u16* __restrict__ W, float* __restrict__ O)
{
  gemm256_body(A, W, O, 1.f, 1);
}

// ---------------- flash attention, 32x32x16 MFMA, swapped QK^T -------------
// (unchanged from round 5)
__global__ __launch_bounds__(256,2) void attn_kernel(
    const u16* __restrict__ Q, const u16* __restrict__ Kg,
    const u16* __restrict__ Vt, u16* __restrict__ Y)
{
  __shared__ alignas(16) u16 Ks[2][64*128];
  __shared__ alignas(16) u16 Vs[2][64*128];
  const int tid = threadIdx.x;
  const int w = tid>>6, l = tid&63;
  const int l31 = l&31, hi = l>>5;
  const int bh_swz = ((blockIdx.x&7)*64 + (blockIdx.x>>3));
  const int bh = bh_swz >> 4;
  const int q0 = (bh_swz & 15) * 128;

  short8 qf[8];
  #pragma unroll
  for (int ds=0; ds<8; ds++)
    qf[ds] = *reinterpret_cast<const short8*>(
        Q + ((size_t)bh*2048 + q0 + w*32 + l31)*128 + ds*16 + hi*8);

  f32x16 accO[4];
  #pragma unroll
  for (int dt=0;dt<4;dt++)
    #pragma unroll
    for (int r=0;r<16;r++) accO[dt][r] = 0.f;
  float mrun = -1e30f, lrun = 0.f;

  int krow_[4], kcol_[4], vd_[4], vkv_[4];
  #pragma unroll
  for (int p=0;p<4;p++){
    int s = p*256 + tid;
    int r = s>>4, c = s&15;
    int cu = c ^ (r&15);
    krow_[p] = r;  kcol_[p] = cu*8;
    vd_[p] = r*2 + (cu>>3);  vkv_[p] = (cu&7)*8;
  }

  auto stage = [&](int buf, int kvt){
    int kv0 = kvt*64;
    #pragma unroll
    for (int p=0;p<4;p++)
      gld16(Kg + ((size_t)bh*2048 + kv0 + krow_[p])*128 + kcol_[p],
            &Ks[buf][(size_t)(p*256 + w*64)*8]);
    #pragma unroll
    for (int p=0;p<4;p++)
      gld16(Vt + ((size_t)bh*128 + vd_[p])*2048 + kv0 + vkv_[p],
            &Vs[buf][(size_t)(p*256 + w*64)*8]);
  };

  stage(0, 0);
  __syncthreads();

  int cur = 0;
  for (int kvt=0; kvt<32; ++kvt){
    if (kvt+1 < 32) stage(cur^1, kvt+1);

    f32x16 accS[2];
    #pragma unroll
    for (int kt=0;kt<2;kt++)
      #pragma unroll
      for (int r=0;r<16;r++) accS[kt][r] = 0.f;
    #pragma unroll
    for (int kt=0;kt<2;kt++){
      #pragma unroll
      for (int ds=0;ds<8;ds++){
        int row = kt*32 + l31;
        int byt = row*256 + (((ds*2 + hi) ^ (row&15))<<4);
        short8 kf = *reinterpret_cast<const short8*>((const char*)(&Ks[cur][0]) + byt);
        accS[kt] = __builtin_amdgcn_mfma_f32_32x32x16_bf16(kf, qf[ds], accS[kt], 0, 0, 0);
      }
    }

    float pmax = accS[0][0];
    #pragma unroll
    for (int kt=0;kt<2;kt++)
      #pragma unroll
      for (int r=0;r<16;r++) pmax = fmaxf(pmax, accS[kt][r]);
    pmax = fmaxf(pmax, __shfl_xor(pmax, 32, 64));
    if (__any(pmax > mrun + 8.f)){
      float mn = fmaxf(mrun, pmax);
      float c = __expf(mrun - mn);
      mrun = mn;
      lrun *= c;
      #pragma unroll
      for (int r=0;r<16;r++){
        int qrow = (r&3) + 8*(r>>2) + 4*hi;
        float cr = __shfl(c, qrow, 64);
        #pragma unroll
        for (int dt=0;dt<4;dt++) accO[dt][r] *= cr;
      }
    }

    float rs = 0.f;
    short8 pa[4];
    #pragma unroll
    for (int kt=0;kt<2;kt++){
      #pragma unroll
      for (int b=0;b<2;b++){
        float e0 = __expf(accS[kt][b*8+0] - mrun);
        float e1 = __expf(accS[kt][b*8+1] - mrun);
        float e2 = __expf(accS[kt][b*8+2] - mrun);
        float e3 = __expf(accS[kt][b*8+3] - mrun);
        float e4 = __expf(accS[kt][b*8+4] - mrun);
        float e5 = __expf(accS[kt][b*8+5] - mrun);
        float e6 = __expf(accS[kt][b*8+6] - mrun);
        float e7 = __expf(accS[kt][b*8+7] - mrun);
        rs += (e0+e1)+(e2+e3)+(e4+e5)+(e6+e7);
        u32 x01 = (u32)f2bf(e0) | ((u32)f2bf(e1)<<16);
        u32 x23 = (u32)f2bf(e2) | ((u32)f2bf(e3)<<16);
        u32 y01 = (u32)f2bf(e4) | ((u32)f2bf(e5)<<16);
        u32 y23 = (u32)f2bf(e6) | ((u32)f2bf(e7)<<16);
        u32 sx_x01 = __shfl_xor(x01, 32, 64);
        u32 sx_x23 = __shfl_xor(x23, 32, 64);
        u32 sx_y01 = __shfl_xor(y01, 32, 64);
        u32 sx_y23 = __shfl_xor(y23, 32, 64);
        int4 wv;
        wv.x = (int)(hi ? sx_y01 : x01);
        wv.y = (int)(hi ? sx_y23 : x23);
        wv.z = (int)(hi ? y01 : sx_x01);
        wv.w = (int)(hi ? y23 : sx_x23);
        pa[kt*2+b] = *reinterpret_cast<short8*>(&wv);
      }
    }
    rs += __shfl_xor(rs, 32, 64);
    lrun += rs;

    #pragma unroll
    for (int dt=0;dt<4;dt++){
      #pragma unroll
      for (int ks=0;ks<4;ks++){
        int d = dt*32 + l31;
        int cu = (d&1)*8 + ks*2 + hi;
        int byt = (d>>1)*256 + ((cu ^ ((d>>1)&15))<<4);
        short8 vf = *reinterpret_cast<const short8*>((const char*)(&Vs[cur][0]) + byt);
        accO[dt] = __builtin_amdgcn_mfma_f32_32x32x16_bf16(pa[ks], vf, accO[dt], 0, 0, 0);
      }
    }

    __syncthreads();
    cur ^= 1;
  }

  const int b_ = bh >> 4, h_ = bh & 15;
  float inv = 1.f / lrun;
  #pragma unroll
  for (int r=0;r<16;r++){
    int qrow = (r&3) + 8*(r>>2) + 4*hi;
    float lr = __shfl(inv, qrow, 64);
    int t = q0 + w*32 + qrow;
    #pragma unroll
    for (int dt=0;dt<4;dt++){
      int d = dt*32 + l31;
      Y[((size_t)b_*2048 + t)*2048 + h_*128 + d] = f2bf(accO[dt][r] * lr);
    }
  }
}

// ---------------- launch ----------------
extern "C" void kernel_launch(void* const* d_in, const int* in_sizes, int n_in,
                              void* d_out, int out_size, void* d_ws, size_t ws_size,
                              hipStream_t stream)
{
  const float* x  = (const float*)d_in[0];
  const float* Wq = (const float*)d_in[1];
  const float* Wk = (const float*)d_in[2];
  const float* Wv = (const float*)d_in[3];
  const float* Wo = (const float*)d_in[4];
  float* out = (float*)d_out;
  char* ws = (char*)d_ws;

  const size_t MB = 1024*1024;
  u16* xb  = (u16*)(ws);            // 16 MiB bf16 x
  u16* wqb = (u16*)(ws + 16*MB);    //  8 MiB
  u16* wkb = (u16*)(ws + 24*MB);    //  8 MiB
  u16* wvb = (u16*)(ws + 32*MB);    //  8 MiB
  u16* wob = (u16*)(ws + 40*MB);    //  8 MiB
  u16* qb  = (u16*)(ws + 48*MB);    // 16 MiB [b][h][t][d]
  u16* kb  = (u16*)(ws + 64*MB);    // 16 MiB [b][h][t][d]
  u16* vtb = (u16*)(ws + 80*MB);    // 16 MiB [b][h][d][t]
  u16* yb  = wqb;                   // 16 MiB overlay: wq/wk dead after gemm_qkv

  cvt_kernel<<<2048, 256, 0, stream>>>(x,  xb,  4096*2048);
  cvt_kernel<<<1024, 256, 0, stream>>>(Wq, wqb, 2048*2048);
  cvt_kernel<<<1024, 256, 0, stream>>>(Wk, wkb, 2048*2048);
  cvt_kernel<<<1024, 256, 0, stream>>>(Wv, wvb, 2048*2048);
  cvt_kernel<<<1024, 256, 0, stream>>>(Wo, wob, 2048*2048);

  const float qscale = 0.08838834764831845f;  // 1/sqrt(128)
  gemm_qkv<<<dim3(8,32,3), 512, 0, stream>>>(xb, wqb, wkb, wvb, qb, kb, vtb, qscale);
  attn_kernel<<<512, 256, 0, stream>>>(qb, kb, vtb, yb);
  gemm_out<<<dim3(8,32), 512, 0, stream>>>(yb, wob, out);
}